// Round 7
// baseline (1200.894 us; speedup 1.0000x reference)
//
#include <hip/hip_runtime.h>
#include <math.h>

// ---------------------------------------------------------------------------
// QuantMlp: out = fq(h)@fq(W2)^T + b2,  h = gelu(fq(LN(x))@fq(W1)^T + b1)
// fq: per-tensor symmetric int8 fake-quant. q-values are small integers.
//
// R8 -> R9: int8 GEMM phase structure coarsened 4 -> 2 phases per K-tile.
// R8 counters: ~3000 cyc/phase vs ~500 cyc pipe floor (MfmaUtil 15%, HBM 15%)
// -> phase/barrier overhead dominates; time has tracked phase count across
// R1->R8. One phase now = {12 ds_read_b128 | 4 gll16 stage | barrier |
// lgkm(0) | 32 MFMA (setprio) | VMC(8) | barrier}.
// Stage schedule: phA(u) stages {A,B}(u+1).k1 (region freed phB(u-1));
// phB(u) stages {A,B}(u+2).k0 (region freed phA(u)). Uniform VMC(8) each
// tail: in-flight 8->12->8, drains exactly what the next phase reads,
// ~2-phase latency cover on every load. NT = K/128 even >= 4 (6 / 24).
// ---------------------------------------------------------------------------

typedef __attribute__((ext_vector_type(4))) float  f4;
typedef __attribute__((ext_vector_type(4))) int    i32x4;
typedef __attribute__((ext_vector_type(4))) unsigned char  uc4;
typedef __attribute__((ext_vector_type(4))) unsigned int   u4;

__device__ __forceinline__ unsigned short f2bf_rn(float f) {
    unsigned u = __float_as_uint(f);
    u += 0x7FFFu + ((u >> 16) & 1u);          // round-to-nearest-even
    return (unsigned short)(u >> 16);
}

// all-threads block -> single device atomicMax of a non-negative float
template <int NW>
__device__ __forceinline__ void block_atomic_max(float v, unsigned* slot,
                                                 float* red, int tid) {
    int lane = tid & 63, wv = tid >> 6;
    #pragma unroll
    for (int m = 32; m; m >>= 1) v = fmaxf(v, __shfl_xor(v, m));
    if (lane == 0) red[wv] = v;
    __syncthreads();
    if (tid == 0) {
        float r = red[0];
        #pragma unroll
        for (int i = 1; i < NW; i++) r = fmaxf(r, red[i]);
        atomicMax(slot, __float_as_uint(r));
    }
}

// async 16B global->LDS (wave-uniform base + lane*16 by construction)
__device__ __forceinline__ void gll16(const void* g, void* l) {
    __builtin_amdgcn_global_load_lds(
        (const __attribute__((address_space(1))) void*)g,
        (__attribute__((address_space(3))) void*)l, 16, 0, 0);
}

// ---------------------------------------------------------------------------
// LayerNorm helpers: one wave per row of 768 (12 floats/lane as 3x float4)
// ---------------------------------------------------------------------------
__device__ __forceinline__ void ln_row(const f4* xr, int lane, f4 v[3],
                                       float& mu, float& rs) {
    float s = 0.f;
    #pragma unroll
    for (int c = 0; c < 3; c++) {
        v[c] = xr[lane + 64 * c];
        s += v[c][0] + v[c][1] + v[c][2] + v[c][3];
    }
    #pragma unroll
    for (int m = 1; m < 64; m <<= 1) s += __shfl_xor(s, m);
    mu = s * (1.0f / 768.0f);
    float q = 0.f;
    #pragma unroll
    for (int c = 0; c < 3; c++) {
        #pragma unroll
        for (int k = 0; k < 4; k++) { float d = v[c][k] - mu; q += d * d; }
    }
    #pragma unroll
    for (int m = 1; m < 64; m <<= 1) q += __shfl_xor(q, m);
    rs = rsqrtf(q * (1.0f / 768.0f) + 1e-5f);
}

__global__ __launch_bounds__(256) void ln_absmax_kernel(
        const float* __restrict__ x, const float* __restrict__ gamma,
        const float* __restrict__ beta, unsigned* __restrict__ slot, long NR) {
    __shared__ float red[4];
    int tid = threadIdx.x, lane = tid & 63, wv = tid >> 6;
    const f4* g4 = (const f4*)gamma;
    const f4* b4 = (const f4*)beta;
    long rstep = (long)gridDim.x * 4;
    float wmax = 0.f;
    for (long row = (long)blockIdx.x * 4 + wv; row < NR; row += rstep) {
        const f4* xr = (const f4*)(x + row * 768);
        f4 v[3]; float mu, rs;
        ln_row(xr, lane, v, mu, rs);
        #pragma unroll
        for (int c = 0; c < 3; c++) {
            f4 g = g4[lane + 64 * c], b = b4[lane + 64 * c];
            #pragma unroll
            for (int k = 0; k < 4; k++) {
                float xn = (v[c][k] - mu) * rs * g[k] + b[k];
                wmax = fmaxf(wmax, fabsf(xn));
            }
        }
    }
    block_atomic_max<4>(wmax, slot, red, tid);
}

// LN + quantize -> int8 (non-narrow act range)
__global__ __launch_bounds__(256) void ln_quant_kernel(
        const float* __restrict__ x, const float* __restrict__ gamma,
        const float* __restrict__ beta, unsigned char* __restrict__ qx,
        const unsigned* __restrict__ amax_bits, long NR) {
    int tid = threadIdx.x, lane = tid & 63, wv = tid >> 6;
    long row = (long)blockIdx.x * 4 + wv;
    if (row >= NR) return;
    float sx = fmaxf(__uint_as_float(*amax_bits) * (1.0f / 128.0f), 1e-12f);
    const f4* xr = (const f4*)(x + row * 768);
    const f4* g4 = (const f4*)gamma;
    const f4* b4 = (const f4*)beta;
    f4 v[3]; float mu, rs;
    ln_row(xr, lane, v, mu, rs);
    uc4* qr = (uc4*)(qx + row * 768);
    #pragma unroll
    for (int c = 0; c < 3; c++) {
        f4 g = g4[lane + 64 * c], b = b4[lane + 64 * c];
        uc4 o;
        #pragma unroll
        for (int k = 0; k < 4; k++) {
            float xn = (v[c][k] - mu) * rs * g[k] + b[k];
            float q = fminf(fmaxf(rintf(xn / sx), -128.0f), 127.0f);
            o[k] = (unsigned char)(int)q;     // two's complement int8
        }
        qr[lane + 64 * c] = o;
    }
}

// ---------------------------------------------------------------------------
// Weight absmax + quantize (fp32 -> int8, narrow range)
// ---------------------------------------------------------------------------
__global__ __launch_bounds__(256) void absmax_kernel(
        const float* __restrict__ w, long n4, unsigned* __restrict__ slot) {
    __shared__ float red[4];
    int tid = threadIdx.x;
    long stride = (long)gridDim.x * 256;
    float mx = 0.f;
    for (long i = (long)blockIdx.x * 256 + tid; i < n4; i += stride) {
        f4 v = ((const f4*)w)[i];
        mx = fmaxf(mx, fmaxf(fmaxf(fabsf(v[0]), fabsf(v[1])),
                             fmaxf(fabsf(v[2]), fabsf(v[3]))));
    }
    block_atomic_max<4>(mx, slot, red, tid);
}

__global__ __launch_bounds__(256) void quant_w_kernel(
        const float* __restrict__ w, unsigned char* __restrict__ qw, long n4,
        const unsigned* __restrict__ amax_bits) {
    long i = (long)blockIdx.x * 256 + threadIdx.x;
    if (i >= n4) return;
    float s = fmaxf(__uint_as_float(*amax_bits) * (1.0f / 127.0f), 1e-12f);
    f4 v = ((const f4*)w)[i];
    uc4 o;
    #pragma unroll
    for (int k = 0; k < 4; k++) {
        float q = fminf(fmaxf(rintf(v[k] / s), -127.0f), 127.0f);
        o[k] = (unsigned char)(int)q;
    }
    ((uc4*)qw)[i] = o;
}

// h bf16 -> int8, IN PLACE: thread reads its own 32B (16 bf16), writes 16 int8
// into the first 16B of the same region. No inter-thread overlap -> race-free.
// Resulting image: k-chunk c (16 values) at byte 32*c of each row.
__global__ __launch_bounds__(256) void quant_h_kernel(
        unsigned int* __restrict__ h, const unsigned* __restrict__ amax_bits,
        long n32) {
    long i = (long)blockIdx.x * 256 + threadIdx.x;
    if (i >= n32) return;
    float s = fmaxf(__uint_as_float(*amax_bits) * (1.0f / 128.0f), 1e-12f);
    u4 d0 = ((const u4*)h)[2 * i];
    u4 d1 = ((const u4*)h)[2 * i + 1];
    u4 o;
    #pragma unroll
    for (int w = 0; w < 4; w++) {
        unsigned r = 0;
        #pragma unroll
        for (int j = 0; j < 2; j++) {
            unsigned dw = (w < 2) ? d0[(w & 1) * 2 + j] : d1[(w & 1) * 2 + j];
            float lo = __uint_as_float(dw << 16);
            float hi = __uint_as_float(dw & 0xFFFF0000u);
            int qa = (int)fminf(fmaxf(rintf(lo / s), -128.0f), 127.0f);
            int qb = (int)fminf(fmaxf(rintf(hi / s), -128.0f), 127.0f);
            r |= ((unsigned)(unsigned char)qa) << (16 * j);
            r |= ((unsigned)(unsigned char)qb) << (16 * j + 8);
        }
        o[w] = r;
    }
    ((u4*)h)[2 * i] = o;
}

// ---------------------------------------------------------------------------
// GEMM: C[M,N] = A[M,K] * B[N,K]^T, int8 operands, int32 accum (exact).
// 256x256 tile, 512 thr = 8 waves (2M x 4N), per-wave 128x64 out.
// Region = 256 rows x 64B (K=64 i8), chunk swizzle c' = c^((r>>1)&3)
// (measured 0 bank conflicts). Tile K=128. LDS 128KB = 2 buf x
// {A.k0,A.k1,B.k0,B.k1} 16KB. Two phases per tile (see header comment).
// GAP: A-image element stride (1 = compact int8; 2 = in-place requantized
// h, 16 used + 16 gap per 32B -> chunk addr gc*32).
// ---------------------------------------------------------------------------
#define AB(b,kh) ((b)*65536 + (kh)*16384)
#define BB(b,kh) ((b)*65536 + 32768 + (kh)*16384)
#define VMC(n) asm volatile("s_waitcnt vmcnt(" #n ")" ::: "memory")
// stage one K-half of the NEXT A and B tiles (4 gll16)
#define SK(eo, rbA, rbB) {                                                    \
    gll16(gA[0] + (long)(eo) * GAP, lds + (rbA) + ldst[0]);                   \
    gll16(gA[1] + (long)(eo) * GAP, lds + (rbA) + ldst[1]);                   \
    gll16(gB[0] + (eo),             lds + (rbB) + ldst[0]);                   \
    gll16(gB[1] + (eo),             lds + (rbB) + ldst[1]); }

#define PHASE2(BUF, KS, STAGE, TAIL) do {                                     \
    i32x4 aF[8]; i32x4 bF[4];                                                 \
    _Pragma("unroll")                                                         \
    for (int m_ = 0; m_ < 8; m_++)                                            \
      aF[m_] = *(const i32x4*)(lds + AB(BUF,KS) + aoff + m_ * 1024);          \
    _Pragma("unroll")                                                         \
    for (int n_ = 0; n_ < 4; n_++)                                            \
      bF[n_] = *(const i32x4*)(lds + BB(BUF,KS) + boff + n_ * 1024);          \
    STAGE                                                                     \
    __builtin_amdgcn_s_barrier();                                             \
    asm volatile("s_waitcnt lgkmcnt(0)" ::: "memory");                        \
    __builtin_amdgcn_s_setprio(1);                                            \
    _Pragma("unroll")                                                         \
    for (int m_ = 0; m_ < 8; m_++)                                            \
      _Pragma("unroll")                                                       \
      for (int n_ = 0; n_ < 4; n_++)                                          \
        acc[m_][n_] = __builtin_amdgcn_mfma_i32_16x16x64_i8(                  \
            aF[m_], bF[n_], acc[m_][n_], 0, 0, 0);                            \
    __builtin_amdgcn_s_setprio(0);                                            \
    TAIL                                                                      \
    __builtin_amdgcn_s_barrier();                                             \
  } while (0)

template <int GAP, int EPI>
__global__ __launch_bounds__(512, 2) void gemm256i(
        const unsigned char* __restrict__ A, const unsigned char* __restrict__ B,
        int K, const unsigned* __restrict__ amaxA_bits,
        const unsigned* __restrict__ amaxB_bits, const float* __restrict__ bias,
        void* __restrict__ Cout, int ldc, unsigned* __restrict__ amax_out) {
    __shared__ __align__(16) char lds[131072];
    __shared__ float red[8];
    int tid = threadIdx.x, lane = tid & 63, wv = tid >> 6;
    int wm = wv >> 2, wn = wv & 3;

    // T1: XCD-contiguous block remap (nwg % 8 == 0 for both launches)
    int nwg = gridDim.x * gridDim.y;
    int flat = blockIdx.y * gridDim.x + blockIdx.x;
    int swz = (flat & 7) * (nwg >> 3) + (flat >> 3);
    int ncol = gridDim.x;
    long rowBase = (long)(swz / ncol) * 256;
    long colBase = (long)(swz % ncol) * 256;

    i32x4 acc[8][4] = {};

    // read-side offsets (bytes; verified layout, 0 bank conflicts)
    int rl = lane & 15, cq = lane >> 4;
    int roff = rl * 64 + ((cq ^ ((rl >> 1) & 3)) * 16);
    int aoff = wm * 8192 + roff;
    int boff = wn * 4096 + roff;

    // stage-side: slot s -> row r = s>>2, global k-chunk gc (inv swizzle)
    const unsigned char* gA[2]; const unsigned char* gB[2]; int ldst[2];
    #pragma unroll
    for (int p = 0; p < 2; p++) {
        int s = p * 512 + tid;
        int r = s >> 2;
        int gc = (s & 3) ^ ((r >> 1) & 3);
        gA[p] = A + (rowBase + r) * (long)K * GAP + gc * 16 * GAP;
        gB[p] = B + (colBase + r) * (long)K + gc * 16;
        ldst[p] = s * 16;
    }

    // prologue: k0(0), k1(0), k0(1); VMC(8) drains k0(0), leaves
    // {k1(0), k0(1)} in flight == steady-state invariant entering phA(0).
    SK(0,   AB(0,0), BB(0,0));
    SK(64,  AB(0,1), BB(0,1));
    SK(128, AB(1,0), BB(1,0));
    VMC(8);
    __builtin_amdgcn_s_barrier();

    // main loop: 2 tiles (4 phases) per iter; covers tiles 0..NT-3.
    // phA(u) stages k1(u+1); phB(u) stages k0(u+2); VMC(8) every tail.
    const int nit = (K >> 8) - 1;
    for (int i = 0; i < nit; i++) {
        PHASE2(0,0, SK(192, AB(1,1), BB(1,1)), VMC(8); );
        PHASE2(0,1, SK(256, AB(0,0), BB(0,0)), VMC(8); );
        PHASE2(1,0, SK(320, AB(0,1), BB(0,1)), VMC(8); );
        PHASE2(1,1, SK(384, AB(1,0), BB(1,0)), VMC(8); );
        gA[0] += 256 * GAP; gA[1] += 256 * GAP; gB[0] += 256; gB[1] += 256;
    }
    // tail tiles NT-2 (buf0), NT-1 (buf1):
    PHASE2(0,0, SK(192, AB(1,1), BB(1,1)), VMC(8); );  // drains k1(NT-2)
    PHASE2(0,1, { },                       VMC(4); );  // drains k0(NT-1)
    PHASE2(1,0, { },                       VMC(0); );  // drains k1(NT-1)
    PHASE2(1,1, { },                               );

    float sA = fmaxf(__uint_as_float(*amaxA_bits) * (1.0f / 128.0f), 1e-12f);
    float sB = fmaxf(__uint_as_float(*amaxB_bits) * (1.0f / 127.0f), 1e-12f);
    float sAB = sA * sB;
    int cr = cq * 4;            // C row base within 16 (row=(lane>>4)*4+reg)
    int cc = rl;                // C col within 16     (col=lane&15)

    float bv[4];
    #pragma unroll
    for (int n = 0; n < 4; n++) bv[n] = bias[colBase + wn * 64 + n * 16 + cc];

    if (EPI == 0) {
        unsigned short* Hm = (unsigned short*)Cout;
        float mx = 0.f;
        #pragma unroll
        for (int m = 0; m < 8; m++) {
            #pragma unroll
            for (int r = 0; r < 4; r++) {
                long ro = (rowBase + wm * 128 + m * 16 + cr + r) * (long)ldc
                          + colBase + wn * 64 + cc;
                #pragma unroll
                for (int n = 0; n < 4; n++) {
                    float v = (float)acc[m][n][r] * sAB + bv[n];
                    float g = 0.5f * v * (1.0f + erff(v * 0.70710678118654752f));
                    mx = fmaxf(mx, fabsf(g));
                    Hm[ro + n * 16] = f2bf_rn(g);
                }
            }
        }
        block_atomic_max<8>(mx, amax_out, red, tid);
    } else {
        float* O = (float*)Cout;
        #pragma unroll
        for (int m = 0; m < 8; m++) {
            #pragma unroll
            for (int r = 0; r < 4; r++) {
                long ro = (rowBase + wm * 128 + m * 16 + cr + r) * (long)ldc
                          + colBase + wn * 64 + cc;
                #pragma unroll
                for (int n = 0; n < 4; n++)
                    O[ro + n * 16] = (float)acc[m][n][r] * sAB + bv[n];
            }
        }
    }
}

// ---------------------------------------------------------------------------
extern "C" void kernel_launch(void* const* d_in, const int* in_sizes, int n_in,
                              void* d_out, int out_size, void* d_ws, size_t ws_size,
                              hipStream_t stream) {
    const float* x     = (const float*)d_in[0];
    const float* gamma = (const float*)d_in[1];
    const float* beta  = (const float*)d_in[2];
    const float* W1    = (const float*)d_in[3];
    const float* b1    = (const float*)d_in[4];
    const float* W2    = (const float*)d_in[5];
    const float* b2    = (const float*)d_in[6];
    float* out = (float*)d_out;

    const int  D  = in_sizes[1];          // 768
    const int  H  = in_sizes[4];          // 3072
    const long NR = (long)in_sizes[0] / D;  // 65536

    char* ws = (char*)d_ws;
    unsigned* amax = (unsigned*)ws;                 // [0]=x [1]=W1 [2]=W2 [3]=h
    unsigned char* qx  = (unsigned char*)(ws + 256);        // NR*D int8
    unsigned char* qw1 = qx  + (size_t)NR * D;              // H*D int8
    unsigned char* qw2 = qw1 + (size_t)H * D;               // D*H int8
    unsigned short* hq = (unsigned short*)(qw2 + (size_t)H * D); // NR*H bf16

    hipMemsetAsync(amax, 0, 16, stream);

    long wn4 = (long)H * D / 4;
    absmax_kernel<<<1024, 256, 0, stream>>>(W1, wn4, amax + 1);
    absmax_kernel<<<1024, 256, 0, stream>>>(W2, wn4, amax + 2);
    ln_absmax_kernel<<<2048, 256, 0, stream>>>(x, gamma, beta, amax + 0, NR);

    quant_w_kernel<<<(unsigned)((wn4 + 255) / 256), 256, 0, stream>>>(W1, qw1, wn4, amax + 1);
    quant_w_kernel<<<(unsigned)((wn4 + 255) / 256), 256, 0, stream>>>(W2, qw2, wn4, amax + 2);
    ln_quant_kernel<<<(unsigned)(NR / 4), 256, 0, stream>>>(x, gamma, beta, qx, amax + 0, NR);

    dim3 g1(H / 256, (unsigned)(NR / 256));   // 12 x 256 = 3072 wg (%8==0)
    gemm256i<1, 0><<<g1, 512, 0, stream>>>(qx, qw1, D, amax + 0, amax + 1, b1,
                                           (void*)hq, H, amax + 3);

    long n32 = NR * (long)H / 16;             // 32B regions of h
    quant_h_kernel<<<(unsigned)((n32 + 255) / 256), 256, 0, stream>>>(
        (unsigned int*)hq, amax + 3, n32);

    dim3 g2(D / 256, (unsigned)(NR / 256));   // 3 x 256 = 768 wg (%8==0)
    gemm256i<2, 1><<<g2, 512, 0, stream>>>((const unsigned char*)hq, qw2, H,
                                           amax + 3, amax + 2, b2,
                                           (void*)out, D, nullptr);
}

// Round 8
// 1058.651 us; speedup vs baseline: 1.1344x; 1.1344x over previous
//
#include <hip/hip_runtime.h>
#include <math.h>

// ---------------------------------------------------------------------------
// QuantMlp: out = fq(h)@fq(W2)^T + b2,  h = gelu(fq(LN(x))@fq(W1)^T + b1)
// fq: per-tensor symmetric int8 fake-quant. q-values are small integers.
//
// R9 -> R10:
//  - K-loop reverted to R8's 4-phase schedule (measured 443 vs R9's 452).
//  - gemm1 epilogue: libm erff replaced by branch-free A&S 7.1.26 rational
//    approx (rcp + exp + 5-term Horner, max abs err 1.5e-7). R9 counters:
//    VALUBusy 60% vs MfmaUtil 14.5% with a VALU-free K-loop -> the 128
//    erff/thread epilogue (serialized at 1 blk/CU) is the dominant VALU
//    cost. Error budget: h already carries bf16 rounding (~2e-2 abs) and
//    int8 quantization (step ~8e-2); 1.5e-7 is invisible.
// ---------------------------------------------------------------------------

typedef __attribute__((ext_vector_type(4))) float  f4;
typedef __attribute__((ext_vector_type(4))) int    i32x4;
typedef __attribute__((ext_vector_type(4))) unsigned char  uc4;
typedef __attribute__((ext_vector_type(4))) unsigned int   u4;

__device__ __forceinline__ unsigned short f2bf_rn(float f) {
    unsigned u = __float_as_uint(f);
    u += 0x7FFFu + ((u >> 16) & 1u);          // round-to-nearest-even
    return (unsigned short)(u >> 16);
}

// Abramowitz-Stegun 7.1.26: erf(x), max abs error ~1.5e-7, branch-free.
__device__ __forceinline__ float erf_fast(float x) {
    float ax = fabsf(x);
    float t = __builtin_amdgcn_rcpf(fmaf(0.3275911f, ax, 1.0f));
    float y = t * (0.254829592f +
              t * (-0.284496736f +
              t * (1.421413741f +
              t * (-1.453152027f +
              t * 1.061405429f))));
    float e = __expf(-ax * ax);
    float r = fmaf(-y, e, 1.0f);              // in [0,1]
    unsigned s = __float_as_uint(x) & 0x80000000u;
    return __uint_as_float(__float_as_uint(r) | s);
}

// all-threads block -> single device atomicMax of a non-negative float
template <int NW>
__device__ __forceinline__ void block_atomic_max(float v, unsigned* slot,
                                                 float* red, int tid) {
    int lane = tid & 63, wv = tid >> 6;
    #pragma unroll
    for (int m = 32; m; m >>= 1) v = fmaxf(v, __shfl_xor(v, m));
    if (lane == 0) red[wv] = v;
    __syncthreads();
    if (tid == 0) {
        float r = red[0];
        #pragma unroll
        for (int i = 1; i < NW; i++) r = fmaxf(r, red[i]);
        atomicMax(slot, __float_as_uint(r));
    }
}

// async 16B global->LDS (wave-uniform base + lane*16 by construction)
__device__ __forceinline__ void gll16(const void* g, void* l) {
    __builtin_amdgcn_global_load_lds(
        (const __attribute__((address_space(1))) void*)g,
        (__attribute__((address_space(3))) void*)l, 16, 0, 0);
}

// ---------------------------------------------------------------------------
// LayerNorm helpers: one wave per row of 768 (12 floats/lane as 3x float4)
// ---------------------------------------------------------------------------
__device__ __forceinline__ void ln_row(const f4* xr, int lane, f4 v[3],
                                       float& mu, float& rs) {
    float s = 0.f;
    #pragma unroll
    for (int c = 0; c < 3; c++) {
        v[c] = xr[lane + 64 * c];
        s += v[c][0] + v[c][1] + v[c][2] + v[c][3];
    }
    #pragma unroll
    for (int m = 1; m < 64; m <<= 1) s += __shfl_xor(s, m);
    mu = s * (1.0f / 768.0f);
    float q = 0.f;
    #pragma unroll
    for (int c = 0; c < 3; c++) {
        #pragma unroll
        for (int k = 0; k < 4; k++) { float d = v[c][k] - mu; q += d * d; }
    }
    #pragma unroll
    for (int m = 1; m < 64; m <<= 1) q += __shfl_xor(q, m);
    rs = rsqrtf(q * (1.0f / 768.0f) + 1e-5f);
}

__global__ __launch_bounds__(256) void ln_absmax_kernel(
        const float* __restrict__ x, const float* __restrict__ gamma,
        const float* __restrict__ beta, unsigned* __restrict__ slot, long NR) {
    __shared__ float red[4];
    int tid = threadIdx.x, lane = tid & 63, wv = tid >> 6;
    const f4* g4 = (const f4*)gamma;
    const f4* b4 = (const f4*)beta;
    long rstep = (long)gridDim.x * 4;
    float wmax = 0.f;
    for (long row = (long)blockIdx.x * 4 + wv; row < NR; row += rstep) {
        const f4* xr = (const f4*)(x + row * 768);
        f4 v[3]; float mu, rs;
        ln_row(xr, lane, v, mu, rs);
        #pragma unroll
        for (int c = 0; c < 3; c++) {
            f4 g = g4[lane + 64 * c], b = b4[lane + 64 * c];
            #pragma unroll
            for (int k = 0; k < 4; k++) {
                float xn = (v[c][k] - mu) * rs * g[k] + b[k];
                wmax = fmaxf(wmax, fabsf(xn));
            }
        }
    }
    block_atomic_max<4>(wmax, slot, red, tid);
}

// LN + quantize -> int8 (non-narrow act range)
__global__ __launch_bounds__(256) void ln_quant_kernel(
        const float* __restrict__ x, const float* __restrict__ gamma,
        const float* __restrict__ beta, unsigned char* __restrict__ qx,
        const unsigned* __restrict__ amax_bits, long NR) {
    int tid = threadIdx.x, lane = tid & 63, wv = tid >> 6;
    long row = (long)blockIdx.x * 4 + wv;
    if (row >= NR) return;
    float sx = fmaxf(__uint_as_float(*amax_bits) * (1.0f / 128.0f), 1e-12f);
    const f4* xr = (const f4*)(x + row * 768);
    const f4* g4 = (const f4*)gamma;
    const f4* b4 = (const f4*)beta;
    f4 v[3]; float mu, rs;
    ln_row(xr, lane, v, mu, rs);
    uc4* qr = (uc4*)(qx + row * 768);
    #pragma unroll
    for (int c = 0; c < 3; c++) {
        f4 g = g4[lane + 64 * c], b = b4[lane + 64 * c];
        uc4 o;
        #pragma unroll
        for (int k = 0; k < 4; k++) {
            float xn = (v[c][k] - mu) * rs * g[k] + b[k];
            float q = fminf(fmaxf(rintf(xn / sx), -128.0f), 127.0f);
            o[k] = (unsigned char)(int)q;     // two's complement int8
        }
        qr[lane + 64 * c] = o;
    }
}

// ---------------------------------------------------------------------------
// Weight absmax + quantize (fp32 -> int8, narrow range)
// ---------------------------------------------------------------------------
__global__ __launch_bounds__(256) void absmax_kernel(
        const float* __restrict__ w, long n4, unsigned* __restrict__ slot) {
    __shared__ float red[4];
    int tid = threadIdx.x;
    long stride = (long)gridDim.x * 256;
    float mx = 0.f;
    for (long i = (long)blockIdx.x * 256 + tid; i < n4; i += stride) {
        f4 v = ((const f4*)w)[i];
        mx = fmaxf(mx, fmaxf(fmaxf(fabsf(v[0]), fabsf(v[1])),
                             fmaxf(fabsf(v[2]), fabsf(v[3]))));
    }
    block_atomic_max<4>(mx, slot, red, tid);
}

__global__ __launch_bounds__(256) void quant_w_kernel(
        const float* __restrict__ w, unsigned char* __restrict__ qw, long n4,
        const unsigned* __restrict__ amax_bits) {
    long i = (long)blockIdx.x * 256 + threadIdx.x;
    if (i >= n4) return;
    float s = fmaxf(__uint_as_float(*amax_bits) * (1.0f / 127.0f), 1e-12f);
    f4 v = ((const f4*)w)[i];
    uc4 o;
    #pragma unroll
    for (int k = 0; k < 4; k++) {
        float q = fminf(fmaxf(rintf(v[k] / s), -127.0f), 127.0f);
        o[k] = (unsigned char)(int)q;
    }
    ((uc4*)qw)[i] = o;
}

// h bf16 -> int8, IN PLACE: thread reads its own 32B (16 bf16), writes 16 int8
// into the first 16B of the same region. No inter-thread overlap -> race-free.
// Resulting image: k-chunk c (16 values) at byte 32*c of each row.
__global__ __launch_bounds__(256) void quant_h_kernel(
        unsigned int* __restrict__ h, const unsigned* __restrict__ amax_bits,
        long n32) {
    long i = (long)blockIdx.x * 256 + threadIdx.x;
    if (i >= n32) return;
    float s = fmaxf(__uint_as_float(*amax_bits) * (1.0f / 128.0f), 1e-12f);
    u4 d0 = ((const u4*)h)[2 * i];
    u4 d1 = ((const u4*)h)[2 * i + 1];
    u4 o;
    #pragma unroll
    for (int w = 0; w < 4; w++) {
        unsigned r = 0;
        #pragma unroll
        for (int j = 0; j < 2; j++) {
            unsigned dw = (w < 2) ? d0[(w & 1) * 2 + j] : d1[(w & 1) * 2 + j];
            float lo = __uint_as_float(dw << 16);
            float hi = __uint_as_float(dw & 0xFFFF0000u);
            int qa = (int)fminf(fmaxf(rintf(lo / s), -128.0f), 127.0f);
            int qb = (int)fminf(fmaxf(rintf(hi / s), -128.0f), 127.0f);
            r |= ((unsigned)(unsigned char)qa) << (16 * j);
            r |= ((unsigned)(unsigned char)qb) << (16 * j + 8);
        }
        o[w] = r;
    }
    ((u4*)h)[2 * i] = o;
}

// ---------------------------------------------------------------------------
// GEMM: C[M,N] = A[M,K] * B[N,K]^T, int8 operands, int32 accum (exact).
// 256x256 tile, 512 thr = 8 waves (2M x 4N), per-wave 128x64 out.
// mfma_i32_16x16x64_i8: per lane 16B = 16 consecutive k. Region = 256 rows
// x 64B (K=64 i8), chunk swizzle c' = c^((r>>1)&3) (0 bank conflicts).
// Tile K=128, LDS 128KB = 2 buf x {A.k0,A.k1,B.k0,B.k1} 16KB. R8 schedule:
// 8 phases / 2 tiles, vmcnt(4) at ph3/ph7 only, vmcnt(0) only in the tail;
// every region overwrite >=1 barrier after its last read. NT=K/128 even >=4.
// GAP: A-image element stride (1 = compact int8; 2 = in-place requantized
// h, 16 used + 16 gap per 32B -> chunk addr gc*32).
// ---------------------------------------------------------------------------
#define AB(b,kh) ((b)*65536 + (kh)*16384)
#define BB(b,kh) ((b)*65536 + 32768 + (kh)*16384)
#define STA(p, eo, rb) gll16(gA[p] + (long)(eo) * GAP, lds + (rb) + ldst[p])
#define STB(p, eo, rb) gll16(gB[p] + (eo), lds + (rb) + ldst[p])
#define VMC(n) asm volatile("s_waitcnt vmcnt(" #n ")" ::: "memory")

#define PHASE(BUF, KS, MB, STAGE, TAIL) do {                                  \
    i32x4 aF[4];                                                              \
    _Pragma("unroll")                                                         \
    for (int m_ = 0; m_ < 4; m_++)                                            \
      aF[m_] = *(const i32x4*)(lds + AB(BUF,KS) + aoff + (MB + m_) * 1024);   \
    if (MB == 0) {                                                            \
      _Pragma("unroll")                                                       \
      for (int n_ = 0; n_ < 4; n_++)                                          \
        bF[n_] = *(const i32x4*)(lds + BB(BUF,KS) + boff + n_ * 1024);        \
    }                                                                         \
    STAGE                                                                     \
    __builtin_amdgcn_s_barrier();                                             \
    asm volatile("s_waitcnt lgkmcnt(0)" ::: "memory");                        \
    __builtin_amdgcn_s_setprio(1);                                            \
    _Pragma("unroll")                                                         \
    for (int m_ = 0; m_ < 4; m_++)                                            \
      _Pragma("unroll")                                                       \
      for (int n_ = 0; n_ < 4; n_++)                                          \
        acc[MB + m_][n_] = __builtin_amdgcn_mfma_i32_16x16x64_i8(             \
            aF[m_], bF[n_], acc[MB + m_][n_], 0, 0, 0);                       \
    __builtin_amdgcn_s_setprio(0);                                            \
    TAIL                                                                      \
    __builtin_amdgcn_s_barrier();                                             \
  } while (0)

template <int GAP, int EPI>
__global__ __launch_bounds__(512, 2) void gemm256i(
        const unsigned char* __restrict__ A, const unsigned char* __restrict__ B,
        int K, const unsigned* __restrict__ amaxA_bits,
        const unsigned* __restrict__ amaxB_bits, const float* __restrict__ bias,
        void* __restrict__ Cout, int ldc, unsigned* __restrict__ amax_out) {
    __shared__ __align__(16) char lds[131072];
    __shared__ float red[8];
    int tid = threadIdx.x, lane = tid & 63, wv = tid >> 6;
    int wm = wv >> 2, wn = wv & 3;

    // T1: XCD-contiguous block remap (nwg % 8 == 0 for both launches)
    int nwg = gridDim.x * gridDim.y;
    int flat = blockIdx.y * gridDim.x + blockIdx.x;
    int swz = (flat & 7) * (nwg >> 3) + (flat >> 3);
    int ncol = gridDim.x;
    long rowBase = (long)(swz / ncol) * 256;
    long colBase = (long)(swz % ncol) * 256;

    i32x4 acc[8][4] = {};
    i32x4 bF[4];

    // read-side offsets (bytes; verified layout, 0 bank conflicts)
    int rl = lane & 15, cq = lane >> 4;
    int roff = rl * 64 + ((cq ^ ((rl >> 1) & 3)) * 16);
    int aoff = wm * 8192 + roff;
    int boff = wn * 4096 + roff;

    // stage-side: slot s -> row r = s>>2, global k-chunk gc (inv swizzle)
    const unsigned char* gA[2]; const unsigned char* gB[2]; int ldst[2];
    #pragma unroll
    for (int p = 0; p < 2; p++) {
        int s = p * 512 + tid;
        int r = s >> 2;
        int gc = (s & 3) ^ ((r >> 1) & 3);
        gA[p] = A + (rowBase + r) * (long)K * GAP + gc * 16 * GAP;
        gB[p] = B + (colBase + r) * (long)K + gc * 16;
        ldst[p] = s * 16;
    }

    // prologue: tile0 fully (k0,k1), then tile1.k0; vmcnt(4) keeps the
    // latter's 4 loads in flight (R8-proven invariant).
    #pragma unroll
    for (int p = 0; p < 2; p++) {
        STA(p, 0,   AB(0,0));
        STA(p, 64,  AB(0,1));
        STB(p, 0,   BB(0,0));
        STB(p, 64,  BB(0,1));
    }
    #pragma unroll
    for (int p = 0; p < 2; p++) {
        STA(p, 128, AB(1,0));
        STB(p, 128, BB(1,0));
    }
    VMC(4);
    __builtin_amdgcn_s_barrier();

    // main loop: tile pairs; eo in i8 k-elements (tile = 128, iter = 256)
    const int nit = (K >> 8) - 1;
    for (int i = 0; i < nit; i++) {
        PHASE(0,0,0, { STA(0,192,AB(1,1)); STA(1,192,AB(1,1)); }, );
        PHASE(0,0,4, { STB(0,192,BB(1,1)); STB(1,192,BB(1,1)); }, );
        PHASE(0,1,0, { STA(0,256,AB(0,0)); STA(1,256,AB(0,0)); }, );
        PHASE(0,1,4, { STB(0,256,BB(0,0)); STB(1,256,BB(0,0)); }, VMC(4); );
        PHASE(1,0,0, { STA(0,320,AB(0,1)); STA(1,320,AB(0,1)); }, );
        PHASE(1,0,4, { STB(0,320,BB(0,1)); STB(1,320,BB(0,1)); }, );
        PHASE(1,1,0, { STA(0,384,AB(1,0)); STA(1,384,AB(1,0)); }, );
        PHASE(1,1,4, { STB(0,384,BB(1,0)); STB(1,384,BB(1,0)); }, VMC(4); );
        gA[0] += 256 * GAP; gA[1] += 256 * GAP; gB[0] += 256; gB[1] += 256;
    }
    // tail tiles NT-2, NT-1: stage last k1, full drain before buf1 reads
    PHASE(0,0,0, { STA(0,192,AB(1,1)); STA(1,192,AB(1,1)); }, );
    PHASE(0,0,4, { STB(0,192,BB(1,1)); STB(1,192,BB(1,1)); }, );
    PHASE(0,1,0, { }, );
    PHASE(0,1,4, { }, VMC(0); );
    PHASE(1,0,0, { }, );
    PHASE(1,0,4, { }, );
    PHASE(1,1,0, { }, );
    PHASE(1,1,4, { }, );

    float sA = fmaxf(__uint_as_float(*amaxA_bits) * (1.0f / 128.0f), 1e-12f);
    float sB = fmaxf(__uint_as_float(*amaxB_bits) * (1.0f / 127.0f), 1e-12f);
    float sAB = sA * sB;
    int cr = cq * 4;            // C row base within 16 (row=(lane>>4)*4+reg)
    int cc = rl;                // C col within 16     (col=lane&15)

    float bv[4];
    #pragma unroll
    for (int n = 0; n < 4; n++) bv[n] = bias[colBase + wn * 64 + n * 16 + cc];

    if (EPI == 0) {
        unsigned short* Hm = (unsigned short*)Cout;
        float mx = 0.f;
        #pragma unroll
        for (int m = 0; m < 8; m++) {
            #pragma unroll
            for (int r = 0; r < 4; r++) {
                long ro = (rowBase + wm * 128 + m * 16 + cr + r) * (long)ldc
                          + colBase + wn * 64 + cc;
                #pragma unroll
                for (int n = 0; n < 4; n++) {
                    float v = (float)acc[m][n][r] * sAB + bv[n];
                    float g = 0.5f * v *
                              (1.0f + erf_fast(v * 0.70710678118654752f));
                    mx = fmaxf(mx, fabsf(g));
                    Hm[ro + n * 16] = f2bf_rn(g);
                }
            }
        }
        block_atomic_max<8>(mx, amax_out, red, tid);
    } else {
        float* O = (float*)Cout;
        #pragma unroll
        for (int m = 0; m < 8; m++) {
            #pragma unroll
            for (int r = 0; r < 4; r++) {
                long ro = (rowBase + wm * 128 + m * 16 + cr + r) * (long)ldc
                          + colBase + wn * 64 + cc;
                #pragma unroll
                for (int n = 0; n < 4; n++)
                    O[ro + n * 16] = (float)acc[m][n][r] * sAB + bv[n];
            }
        }
    }
}

// ---------------------------------------------------------------------------
extern "C" void kernel_launch(void* const* d_in, const int* in_sizes, int n_in,
                              void* d_out, int out_size, void* d_ws, size_t ws_size,
                              hipStream_t stream) {
    const float* x     = (const float*)d_in[0];
    const float* gamma = (const float*)d_in[1];
    const float* beta  = (const float*)d_in[2];
    const float* W1    = (const float*)d_in[3];
    const float* b1    = (const float*)d_in[4];
    const float* W2    = (const float*)d_in[5];
    const float* b2    = (const float*)d_in[6];
    float* out = (float*)d_out;

    const int  D  = in_sizes[1];          // 768
    const int  H  = in_sizes[4];          // 3072
    const long NR = (long)in_sizes[0] / D;  // 65536

    char* ws = (char*)d_ws;
    unsigned* amax = (unsigned*)ws;                 // [0]=x [1]=W1 [2]=W2 [3]=h
    unsigned char* qx  = (unsigned char*)(ws + 256);        // NR*D int8
    unsigned char* qw1 = qx  + (size_t)NR * D;              // H*D int8
    unsigned char* qw2 = qw1 + (size_t)H * D;               // D*H int8
    unsigned short* hq = (unsigned short*)(qw2 + (size_t)H * D); // NR*H bf16

    hipMemsetAsync(amax, 0, 16, stream);

    long wn4 = (long)H * D / 4;
    absmax_kernel<<<1024, 256, 0, stream>>>(W1, wn4, amax + 1);
    absmax_kernel<<<1024, 256, 0, stream>>>(W2, wn4, amax + 2);
    ln_absmax_kernel<<<2048, 256, 0, stream>>>(x, gamma, beta, amax + 0, NR);

    quant_w_kernel<<<(unsigned)((wn4 + 255) / 256), 256, 0, stream>>>(W1, qw1, wn4, amax + 1);
    quant_w_kernel<<<(unsigned)((wn4 + 255) / 256), 256, 0, stream>>>(W2, qw2, wn4, amax + 2);
    ln_quant_kernel<<<(unsigned)(NR / 4), 256, 0, stream>>>(x, gamma, beta, qx, amax + 0, NR);

    dim3 g1(H / 256, (unsigned)(NR / 256));   // 12 x 256 = 3072 wg (%8==0)
    gemm256i<1, 0><<<g1, 512, 0, stream>>>(qx, qw1, D, amax + 0, amax + 1, b1,
                                           (void*)hq, H, amax + 3);

    long n32 = NR * (long)H / 16;             // 32B regions of h
    quant_h_kernel<<<(unsigned)((n32 + 255) / 256), 256, 0, stream>>>(
        (unsigned int*)hq, amax + 3, n32);

    dim3 g2(D / 256, (unsigned)(NR / 256));   // 3 x 256 = 768 wg (%8==0)
    gemm256i<2, 1><<<g2, 512, 0, stream>>>((const unsigned char*)hq, qw2, H,
                                           amax + 3, amax + 2, b2,
                                           (void*)out, D, nullptr);
}